// Round 1
// baseline (10920.049 us; speedup 1.0000x reference)
//
#include <hip/hip_runtime.h>
#include <math.h>

#define F 256

typedef __attribute__((ext_vector_type(8))) short short8;
typedef __attribute__((ext_vector_type(4))) float f32x4;

__device__ __forceinline__ unsigned short f2bf(float f) {
  union { float f; unsigned u; } v; v.f = f;
  unsigned r = (v.u + 0x7fffu + ((v.u >> 16) & 1u)) >> 16;
  return (unsigned short)r;
}
__device__ __forceinline__ float bf2f(unsigned short h) {
  union { unsigned u; float f; } v; v.u = ((unsigned)h) << 16;
  return v.f;
}

// Kernel 1: W[k][n] fp32 -> Wt[n][k] bf16 (transpose+convert), 65536 elems
__global__ void prep_wt(const float* __restrict__ W, unsigned short* __restrict__ Wt) {
  int idx = blockIdx.x * 256 + threadIdx.x;
  int k = idx >> 8, n = idx & 255;
  Wt[n * F + k] = f2bf(W[k * F + n]);
}

// Kernel 2: one wave per edge; hi[row] += val * x[col]; lane handles 4 floats.
__global__ void scatter_edges(const float* __restrict__ x, const int* __restrict__ rows,
                              const int* __restrict__ cols, const float* __restrict__ vals,
                              float* hi, int E) {
  int gid = blockIdx.x * blockDim.x + threadIdx.x;
  int e = gid >> 6;
  if (e >= E) return;
  int lane = threadIdx.x & 63;
  int r = rows[e], c = cols[e];
  float v = vals[e];
  float4 xv = ((const float4*)(x + (size_t)c * F))[lane];
  float* dst = hi + (size_t)r * F + (lane << 2);
  atomicAdd(dst + 0, v * xv.x);
  atomicAdd(dst + 1, v * xv.y);
  atomicAdd(dst + 2, v * xv.z);
  atomicAdd(dst + 3, v * xv.w);
}

// Kernel 3: per 64-row tile: support = (1-a)*hi + a*h0 (bf16 in LDS),
// C = support @ W via mfma 16x16x32 bf16, out = theta*C + (1-theta)*support.
// hi and out may alias (in-place): all reads of this block's rows happen
// before any write (LDS staging + syncthreads).
__global__ __launch_bounds__(256) void gemm_epilogue(
    const float* hi, const float* __restrict__ h0,
    const unsigned short* __restrict__ Wt, float* out,
    const float* __restrict__ alpha_p, const float* __restrict__ lamda_p,
    const int* __restrict__ l_p, int N) {
  __shared__ unsigned short sup[64][264];  // +8 pad: 2-way bank alias only (free)

  const float alpha = *alpha_p;
  const float theta = logf(*lamda_p / (float)(*l_p) + 1.0f);
  const float one_m_a = 1.0f - alpha;
  const float one_m_t = 1.0f - theta;

  const int m0 = blockIdx.x * 64;
  const int t = threadIdx.x;

  // ---- stage support tile (64 rows x 256 cols) into LDS as bf16 ----
#pragma unroll
  for (int i = 0; i < 16; ++i) {
    int f = t + i * 256;          // float4 slot in 64x64 grid
    int row = f >> 6, c4 = f & 63;
    int g_row = m0 + row;
    float4 a = make_float4(0.f, 0.f, 0.f, 0.f);
    float4 b = make_float4(0.f, 0.f, 0.f, 0.f);
    if (g_row < N) {
      a = ((const float4*)(hi + (size_t)g_row * F))[c4];
      b = ((const float4*)(h0 + (size_t)g_row * F))[c4];
    }
    unsigned short* p = &sup[row][c4 << 2];
    p[0] = f2bf(one_m_a * a.x + alpha * b.x);
    p[1] = f2bf(one_m_a * a.y + alpha * b.y);
    p[2] = f2bf(one_m_a * a.z + alpha * b.z);
    p[3] = f2bf(one_m_a * a.w + alpha * b.w);
  }
  __syncthreads();

  // ---- MFMA: wave w does rows [w*16, w*16+16), all 256 cols ----
  const int wave = t >> 6, lane = t & 63;
  const int quad = lane >> 4, lcol = lane & 15;
  const int mrow = wave * 16;

  f32x4 acc[16];
#pragma unroll
  for (int n = 0; n < 16; ++n) acc[n] = (f32x4){0.f, 0.f, 0.f, 0.f};

#pragma unroll
  for (int k = 0; k < 8; ++k) {  // K chunks of 32
    // A frag: sup[mrow+lcol][k*32 + quad*8 .. +8]  (16B aligned)
    short8 afrag = *(const short8*)&sup[mrow + lcol][k * 32 + quad * 8];
#pragma unroll
    for (int n = 0; n < 16; ++n) {
      // B frag: Wt[n*16+lcol][k*32 + quad*8 .. +8]
      short8 bfrag = *(const short8*)&Wt[(size_t)(n * 16 + lcol) * F + k * 32 + quad * 8];
      acc[n] = __builtin_amdgcn_mfma_f32_16x16x32_bf16(afrag, bfrag, acc[n], 0, 0, 0);
    }
  }

  // ---- epilogue: out = theta*acc + (1-theta)*support ----
#pragma unroll
  for (int n = 0; n < 16; ++n) {
#pragma unroll
    for (int r = 0; r < 4; ++r) {
      int lrow = mrow + quad * 4 + r;     // local row in tile
      int col = n * 16 + lcol;
      int g_row = m0 + lrow;
      if (g_row < N) {
        float s = bf2f(sup[lrow][col]);
        out[(size_t)g_row * F + col] = theta * acc[n][r] + one_m_t * s;
      }
    }
  }
}

extern "C" void kernel_launch(void* const* d_in, const int* in_sizes, int n_in,
                              void* d_out, int out_size, void* d_ws, size_t ws_size,
                              hipStream_t stream) {
  const float* x     = (const float*)d_in[0];
  const int*   rows  = (const int*)d_in[1];
  const int*   cols  = (const int*)d_in[2];
  const float* vals  = (const float*)d_in[3];
  const float* h0    = (const float*)d_in[4];
  const float* W     = (const float*)d_in[5];
  const float* lamda = (const float*)d_in[6];
  const float* alpha = (const float*)d_in[7];
  const int*   lp    = (const int*)d_in[8];

  const int E = in_sizes[1];
  const int N = in_sizes[0] / F;

  unsigned short* Wt = (unsigned short*)d_ws;  // 128 KB
  float* out = (float*)d_out;

  // d_out doubles as the hi accumulator (poisoned every call -> zero it)
  hipMemsetAsync(d_out, 0, (size_t)N * F * sizeof(float), stream);

  prep_wt<<<(F * F) / 256, 256, 0, stream>>>(W, Wt);

  long long threads = (long long)E * 64;
  int blocks = (int)((threads + 255) / 256);
  scatter_edges<<<blocks, 256, 0, stream>>>(x, rows, cols, vals, out, E);

  gemm_epilogue<<<(N + 63) / 64, 256, 0, stream>>>(out, h0, Wt, out,
                                                   alpha, lamda, lp, N);
}

// Round 2
// 1181.119 us; speedup vs baseline: 9.2455x; 9.2455x over previous
//
#include <hip/hip_runtime.h>
#include <math.h>

#define F 256
#define NROWS_MAX 100000

typedef __attribute__((ext_vector_type(8))) short short8;
typedef __attribute__((ext_vector_type(4))) float f32x4;

__device__ __forceinline__ unsigned short f2bf(float f) {
  union { float f; unsigned u; } v; v.f = f;
  unsigned r = (v.u + 0x7fffu + ((v.u >> 16) & 1u)) >> 16;
  return (unsigned short)r;
}
__device__ __forceinline__ float bf2f(unsigned short h) {
  union { unsigned u; float f; } v; v.u = ((unsigned)h) << 16;
  return v.f;
}

// ---- W[k][n] fp32 -> Wt[n][k] bf16 ----
__global__ void prep_wt(const float* __restrict__ W, unsigned short* __restrict__ Wt) {
  int idx = blockIdx.x * 256 + threadIdx.x;
  int k = idx >> 8, n = idx & 255;
  Wt[n * F + k] = f2bf(W[k * F + n]);
}

// ---- CSR build: histogram ----
__global__ void hist_rows(const int* __restrict__ rows, int* counts, int E) {
  int e = blockIdx.x * 256 + threadIdx.x;
  if (e < E) atomicAdd(&counts[rows[e]], 1);
}

// ---- scan step 1: per-256 block local exclusive scan + block totals ----
__global__ void scan1(const int* __restrict__ counts, int* row_start, int* blk, int N) {
  __shared__ int tmp[256];
  int t = threadIdx.x;
  int i = blockIdx.x * 256 + t;
  int v = (i < N) ? counts[i] : 0;
  tmp[t] = v;
  __syncthreads();
#pragma unroll
  for (int off = 1; off < 256; off <<= 1) {
    int a = (t >= off) ? tmp[t - off] : 0;
    __syncthreads();
    tmp[t] += a;
    __syncthreads();
  }
  if (i < N) row_start[i] = tmp[t] - v;       // local exclusive
  if (t == 255) blk[blockIdx.x] = tmp[255];   // block total
}

// ---- scan step 2: exclusive scan of block totals (NB <= 512), one block ----
__global__ void scan2(int* blk, int NB) {
  __shared__ int tmp[512];
  int t = threadIdx.x;
  int v = (t < NB) ? blk[t] : 0;
  tmp[t] = v;
  __syncthreads();
#pragma unroll
  for (int off = 1; off < 512; off <<= 1) {
    int a = (t >= off) ? tmp[t - off] : 0;
    __syncthreads();
    tmp[t] += a;
    __syncthreads();
  }
  if (t < NB) blk[t] = tmp[t] - v;            // exclusive
}

// ---- scan step 3: add block offsets; init fill ptrs; cap row_start[N] ----
__global__ void scan3(const int* __restrict__ counts, int* row_start,
                      const int* __restrict__ blk, int* fill_ptr, int N) {
  int i = blockIdx.x * 256 + threadIdx.x;
  if (i >= N) return;
  int rs = row_start[i] + blk[i >> 8];
  row_start[i] = rs;
  fill_ptr[i] = rs;
  if (i == N - 1) row_start[N] = rs + counts[i];
}

// ---- CSR fill: edges packed as (col, val_bits) int2 ----
__global__ void fill_csr(const int* __restrict__ rows, const int* __restrict__ cols,
                         const float* __restrict__ vals, int* fill_ptr,
                         int2* __restrict__ edges, int E) {
  int e = blockIdx.x * 256 + threadIdx.x;
  if (e >= E) return;
  int r = rows[e];
  int pos = atomicAdd(&fill_ptr[r], 1);
  edges[pos] = make_int2(cols[e], __float_as_int(vals[e]));
}

// ---- gather: one wave per row, atomic-free; fuses support blend ----
__global__ __launch_bounds__(256) void gather_rows(
    const float* __restrict__ x, const float* __restrict__ h0,
    const int* __restrict__ row_start, const int2* __restrict__ edges,
    float* __restrict__ support, const float* __restrict__ alpha_p, int N) {
  int gid = blockIdx.x * 256 + threadIdx.x;
  int r = gid >> 6;
  if (r >= N) return;
  int lane = threadIdx.x & 63;
  float alpha = *alpha_p;
  int s = row_start[r], e = row_start[r + 1];
  float4 acc = make_float4(0.f, 0.f, 0.f, 0.f);
  int j = s;
  if (j < e) {
    int2 ed = edges[j];
    for (; j < e; ) {
      int2 cur = ed;
      ++j;
      if (j < e) ed = edges[j];               // prefetch next edge record
      float v = __int_as_float(cur.y);
      float4 xv = ((const float4*)(x + (size_t)cur.x * F))[lane];
      acc.x += v * xv.x; acc.y += v * xv.y;
      acc.z += v * xv.z; acc.w += v * xv.w;
    }
  }
  float4 b = ((const float4*)(h0 + (size_t)r * F))[lane];
  float om = 1.0f - alpha;
  float4 o;
  o.x = om * acc.x + alpha * b.x;
  o.y = om * acc.y + alpha * b.y;
  o.z = om * acc.z + alpha * b.z;
  o.w = om * acc.w + alpha * b.w;
  ((float4*)(support + (size_t)r * F))[lane] = o;
}

// ---- GEMM + epilogue: out = theta*(support@W) + (1-theta)*support ----
// support and out alias (in-place): tile fully staged to LDS before writes.
__global__ __launch_bounds__(256) void gemm_epilogue(
    const float* support, const unsigned short* __restrict__ Wt, float* out,
    const float* __restrict__ lamda_p, const int* __restrict__ l_p, int N) {
  __shared__ unsigned short sup[64][264];  // +8 pad: 2-way bank alias (free)

  const float theta = logf(*lamda_p / (float)(*l_p) + 1.0f);
  const float one_m_t = 1.0f - theta;

  const int m0 = blockIdx.x * 64;
  const int t = threadIdx.x;

#pragma unroll
  for (int i = 0; i < 16; ++i) {
    int f = t + i * 256;
    int row = f >> 6, c4 = f & 63;
    int g_row = m0 + row;
    float4 a = make_float4(0.f, 0.f, 0.f, 0.f);
    if (g_row < N) a = ((const float4*)(support + (size_t)g_row * F))[c4];
    unsigned short* p = &sup[row][c4 << 2];
    p[0] = f2bf(a.x); p[1] = f2bf(a.y); p[2] = f2bf(a.z); p[3] = f2bf(a.w);
  }
  __syncthreads();

  const int wave = t >> 6, lane = t & 63;
  const int quad = lane >> 4, lcol = lane & 15;
  const int mrow = wave * 16;

  f32x4 acc[16];
#pragma unroll
  for (int n = 0; n < 16; ++n) acc[n] = (f32x4){0.f, 0.f, 0.f, 0.f};

#pragma unroll
  for (int k = 0; k < 8; ++k) {
    short8 afrag = *(const short8*)&sup[mrow + lcol][k * 32 + quad * 8];
#pragma unroll
    for (int n = 0; n < 16; ++n) {
      short8 bfrag = *(const short8*)&Wt[(size_t)(n * 16 + lcol) * F + k * 32 + quad * 8];
      acc[n] = __builtin_amdgcn_mfma_f32_16x16x32_bf16(afrag, bfrag, acc[n], 0, 0, 0);
    }
  }

#pragma unroll
  for (int n = 0; n < 16; ++n) {
#pragma unroll
    for (int r = 0; r < 4; ++r) {
      int lrow = mrow + quad * 4 + r;
      int col = n * 16 + lcol;
      int g_row = m0 + lrow;
      if (g_row < N) {
        float s = bf2f(sup[lrow][col]);
        out[(size_t)g_row * F + col] = theta * acc[n][r] + one_m_t * s;
      }
    }
  }
}

extern "C" void kernel_launch(void* const* d_in, const int* in_sizes, int n_in,
                              void* d_out, int out_size, void* d_ws, size_t ws_size,
                              hipStream_t stream) {
  const float* x     = (const float*)d_in[0];
  const int*   rows  = (const int*)d_in[1];
  const int*   cols  = (const int*)d_in[2];
  const float* vals  = (const float*)d_in[3];
  const float* h0    = (const float*)d_in[4];
  const float* W     = (const float*)d_in[5];
  const float* lamda = (const float*)d_in[6];
  const float* alpha = (const float*)d_in[7];
  const int*   lp    = (const int*)d_in[8];

  const int E = in_sizes[1];
  const int N = in_sizes[0] / F;

  // ---- workspace layout (bytes) ----
  char* ws = (char*)d_ws;
  unsigned short* Wt = (unsigned short*)ws;                 // 131072
  int* counts    = (int*)(ws + 131072);                     // N*4
  int* row_start = (int*)(ws + 131072 + 400000);            // (N+1)*4
  int* fill_ptr  = (int*)(ws + 131072 + 400000 + 400256);   // N*4
  int* blk       = (int*)(ws + 131072 + 400000 + 400256 + 400000);      // 2048
  int2* edges    = (int2*)(ws + 131072 + 400000 + 400256 + 400000 + 2048); // E*8

  float* out = (float*)d_out;

  // counts must be zero every call (ws is re-poisoned)
  hipMemsetAsync(counts, 0, (size_t)N * sizeof(int), stream);

  prep_wt<<<(F * F) / 256, 256, 0, stream>>>(W, Wt);

  int eb = (E + 255) / 256;
  int nb = (N + 255) / 256;  // = 391 for N=100000, fits scan2's 512

  hist_rows<<<eb, 256, 0, stream>>>(rows, counts, E);
  scan1<<<nb, 256, 0, stream>>>(counts, row_start, blk, N);
  scan2<<<1, 512, 0, stream>>>(blk, nb);
  scan3<<<nb, 256, 0, stream>>>(counts, row_start, blk, fill_ptr, N);
  fill_csr<<<eb, 256, 0, stream>>>(rows, cols, vals, fill_ptr, edges, E);

  // one wave per row: 64 waves -> 16 blocks per 1024 rows
  int gather_blocks = (N * 64 + 255) / 256;
  gather_rows<<<gather_blocks, 256, 0, stream>>>(x, h0, row_start, edges,
                                                 out, alpha, N);

  gemm_epilogue<<<(N + 63) / 64, 256, 0, stream>>>(out, Wt, out, lamda, lp, N);
}

// Round 3
// 1159.429 us; speedup vs baseline: 9.4185x; 1.0187x over previous
//
#include <hip/hip_runtime.h>
#include <math.h>

#define F 256

typedef __attribute__((ext_vector_type(8))) short short8;
typedef __attribute__((ext_vector_type(4))) float f32x4;
typedef __attribute__((ext_vector_type(2))) int i32x2;
typedef __attribute__((ext_vector_type(4))) unsigned short u16x4;
typedef __attribute__((ext_vector_type(8))) unsigned short u16x8;

__device__ __forceinline__ unsigned short f2bf(float f) {
  union { float f; unsigned u; } v; v.f = f;
  unsigned r = (v.u + 0x7fffu + ((v.u >> 16) & 1u)) >> 16;
  return (unsigned short)r;
}
__device__ __forceinline__ float bf2f(unsigned short h) {
  union { unsigned u; float f; } v; v.u = ((unsigned)h) << 16;
  return v.f;
}

// ---- prep: blocks [0,256): W[k][n] fp32 -> Wt[n][k] bf16.
//            blocks [256,..): x fp32 -> xb bf16 (8 elems/thread, NT reads).
__global__ void prep(const float* __restrict__ W, unsigned short* __restrict__ Wt,
                     const float* __restrict__ x, unsigned short* __restrict__ xb,
                     int NF, int do_xb) {
  if (blockIdx.x < 256) {
    int idx = blockIdx.x * 256 + threadIdx.x;
    int k = idx >> 8, n = idx & 255;
    Wt[n * F + k] = f2bf(W[k * F + n]);
    return;
  }
  if (!do_xb) return;
  int i0 = (blockIdx.x - 256) * 2048 + threadIdx.x * 8;
  if (i0 + 8 <= NF) {
    f32x4 a = __builtin_nontemporal_load((const f32x4*)(x + i0));
    f32x4 b = __builtin_nontemporal_load((const f32x4*)(x + i0 + 4));
    u16x8 o;
    o[0] = f2bf(a.x); o[1] = f2bf(a.y); o[2] = f2bf(a.z); o[3] = f2bf(a.w);
    o[4] = f2bf(b.x); o[5] = f2bf(b.y); o[6] = f2bf(b.z); o[7] = f2bf(b.w);
    *(u16x8*)(xb + i0) = o;
  } else {
    for (int i = i0; i < NF; ++i) xb[i] = f2bf(x[i]);
  }
}

// ---- CSR build: histogram ----
__global__ void hist_rows(const int* __restrict__ rows, int* counts, int E) {
  int e = blockIdx.x * 256 + threadIdx.x;
  if (e < E) atomicAdd(&counts[__builtin_nontemporal_load(&rows[e])], 1);
}

// ---- scan step 1: per-256 block local exclusive scan + block totals ----
__global__ void scan1(const int* __restrict__ counts, int* row_start, int* blk, int N) {
  __shared__ int tmp[256];
  int t = threadIdx.x;
  int i = blockIdx.x * 256 + t;
  int v = (i < N) ? counts[i] : 0;
  tmp[t] = v;
  __syncthreads();
#pragma unroll
  for (int off = 1; off < 256; off <<= 1) {
    int a = (t >= off) ? tmp[t - off] : 0;
    __syncthreads();
    tmp[t] += a;
    __syncthreads();
  }
  if (i < N) row_start[i] = tmp[t] - v;
  if (t == 255) blk[blockIdx.x] = tmp[255];
}

// ---- scan step 2: exclusive scan of block totals (NB <= 512), one block ----
__global__ void scan2(int* blk, int NB) {
  __shared__ int tmp[512];
  int t = threadIdx.x;
  int v = (t < NB) ? blk[t] : 0;
  tmp[t] = v;
  __syncthreads();
#pragma unroll
  for (int off = 1; off < 512; off <<= 1) {
    int a = (t >= off) ? tmp[t - off] : 0;
    __syncthreads();
    tmp[t] += a;
    __syncthreads();
  }
  if (t < NB) blk[t] = tmp[t] - v;
}

// ---- scan step 3: add block offsets; init fill ptrs; cap row_start[N] ----
__global__ void scan3(const int* __restrict__ counts, int* row_start,
                      const int* __restrict__ blk, int* fill_ptr, int N) {
  int i = blockIdx.x * 256 + threadIdx.x;
  if (i >= N) return;
  int rs = row_start[i] + blk[i >> 8];
  row_start[i] = rs;
  fill_ptr[i] = rs;
  if (i == N - 1) row_start[N] = rs + counts[i];
}

// ---- CSR fill: edges packed as (col, val_bits) ----
__global__ void fill_csr(const int* __restrict__ rows, const int* __restrict__ cols,
                         const float* __restrict__ vals, int* fill_ptr,
                         int2* __restrict__ edges, int E) {
  int e = blockIdx.x * 256 + threadIdx.x;
  if (e >= E) return;
  int r = __builtin_nontemporal_load(&rows[e]);
  int c = __builtin_nontemporal_load(&cols[e]);
  float v = __builtin_nontemporal_load(&vals[e]);
  int pos = atomicAdd(&fill_ptr[r], 1);
  edges[pos] = make_int2(c, __float_as_int(v));
}

// ---- gather (bf16 x): one wave per row, atomic-free, pipelined ----
__global__ __launch_bounds__(256) void gather_rows_bf16(
    const unsigned short* __restrict__ xb, const float* __restrict__ h0,
    const int* __restrict__ row_start, const i32x2* __restrict__ edges,
    float* __restrict__ support, const float* __restrict__ alpha_p, int N) {
  int gid = blockIdx.x * 256 + threadIdx.x;
  int r = gid >> 6;
  if (r >= N) return;
  int lane = threadIdx.x & 63;
  float alpha = *alpha_p;
  int s = row_start[r], e = row_start[r + 1];
  f32x4 acc = (f32x4){0.f, 0.f, 0.f, 0.f};
  if (s < e) {
    i32x2 ed = __builtin_nontemporal_load(&edges[s]);
    u16x4 xv = *(const u16x4*)(xb + (size_t)ed.x * F + lane * 4);
    for (int j = s; j < e; ++j) {
      i32x2 cur = ed;
      u16x4 xc = xv;
      if (j + 1 < e) {
        ed = __builtin_nontemporal_load(&edges[j + 1]);
        xv = *(const u16x4*)(xb + (size_t)ed.x * F + lane * 4);
      }
      float v = __int_as_float(cur.y);
      acc.x += v * bf2f(xc[0]);
      acc.y += v * bf2f(xc[1]);
      acc.z += v * bf2f(xc[2]);
      acc.w += v * bf2f(xc[3]);
    }
  }
  f32x4 b = __builtin_nontemporal_load((const f32x4*)(h0 + (size_t)r * F) + lane);
  float om = 1.0f - alpha;
  f32x4 o = om * acc + alpha * b;
  *((f32x4*)(support + (size_t)r * F) + lane) = o;
}

// ---- gather (fp32 x) fallback if ws can't hold xb ----
__global__ __launch_bounds__(256) void gather_rows_f32(
    const float* __restrict__ x, const float* __restrict__ h0,
    const int* __restrict__ row_start, const i32x2* __restrict__ edges,
    float* __restrict__ support, const float* __restrict__ alpha_p, int N) {
  int gid = blockIdx.x * 256 + threadIdx.x;
  int r = gid >> 6;
  if (r >= N) return;
  int lane = threadIdx.x & 63;
  float alpha = *alpha_p;
  int s = row_start[r], e = row_start[r + 1];
  f32x4 acc = (f32x4){0.f, 0.f, 0.f, 0.f};
  if (s < e) {
    i32x2 ed = __builtin_nontemporal_load(&edges[s]);
    f32x4 xv = *((const f32x4*)(x + (size_t)ed.x * F) + lane);
    for (int j = s; j < e; ++j) {
      i32x2 cur = ed;
      f32x4 xc = xv;
      if (j + 1 < e) {
        ed = __builtin_nontemporal_load(&edges[j + 1]);
        xv = *((const f32x4*)(x + (size_t)ed.x * F) + lane);
      }
      float v = __int_as_float(cur.y);
      acc += v * xc;
    }
  }
  f32x4 b = __builtin_nontemporal_load((const f32x4*)(h0 + (size_t)r * F) + lane);
  float om = 1.0f - alpha;
  f32x4 o = om * acc + alpha * b;
  *((f32x4*)(support + (size_t)r * F) + lane) = o;
}

// ---- GEMM + epilogue: out = theta*(support@W) + (1-theta)*support ----
// support and out alias (in-place): tile fully staged to LDS before writes.
__global__ __launch_bounds__(256) void gemm_epilogue(
    const float* support, const unsigned short* __restrict__ Wt, float* out,
    const float* __restrict__ lamda_p, const int* __restrict__ l_p, int N) {
  __shared__ unsigned short sup[64][264];  // +8 pad: 2-way bank alias (free)

  const float theta = logf(*lamda_p / (float)(*l_p) + 1.0f);
  const float one_m_t = 1.0f - theta;

  const int m0 = blockIdx.x * 64;
  const int t = threadIdx.x;

#pragma unroll
  for (int i = 0; i < 16; ++i) {
    int f = t + i * 256;
    int row = f >> 6, c4 = f & 63;
    int g_row = m0 + row;
    f32x4 a = (f32x4){0.f, 0.f, 0.f, 0.f};
    if (g_row < N)
      a = __builtin_nontemporal_load((const f32x4*)(support + (size_t)g_row * F) + c4);
    unsigned short* p = &sup[row][c4 << 2];
    p[0] = f2bf(a.x); p[1] = f2bf(a.y); p[2] = f2bf(a.z); p[3] = f2bf(a.w);
  }
  __syncthreads();

  const int wave = t >> 6, lane = t & 63;
  const int quad = lane >> 4, lcol = lane & 15;
  const int mrow = wave * 16;

  f32x4 acc[16];
#pragma unroll
  for (int n = 0; n < 16; ++n) acc[n] = (f32x4){0.f, 0.f, 0.f, 0.f};

#pragma unroll
  for (int k = 0; k < 8; ++k) {
    short8 afrag = *(const short8*)&sup[mrow + lcol][k * 32 + quad * 8];
#pragma unroll
    for (int n = 0; n < 16; ++n) {
      short8 bfrag = *(const short8*)&Wt[(size_t)(n * 16 + lcol) * F + k * 32 + quad * 8];
      acc[n] = __builtin_amdgcn_mfma_f32_16x16x32_bf16(afrag, bfrag, acc[n], 0, 0, 0);
    }
  }

#pragma unroll
  for (int n = 0; n < 16; ++n) {
#pragma unroll
    for (int r = 0; r < 4; ++r) {
      int lrow = mrow + quad * 4 + r;
      int col = n * 16 + lcol;
      int g_row = m0 + lrow;
      if (g_row < N) {
        float s = bf2f(sup[lrow][col]);
        __builtin_nontemporal_store(theta * acc[n][r] + one_m_t * s,
                                    &out[(size_t)g_row * F + col]);
      }
    }
  }
}

extern "C" void kernel_launch(void* const* d_in, const int* in_sizes, int n_in,
                              void* d_out, int out_size, void* d_ws, size_t ws_size,
                              hipStream_t stream) {
  const float* x     = (const float*)d_in[0];
  const int*   rows  = (const int*)d_in[1];
  const int*   cols  = (const int*)d_in[2];
  const float* vals  = (const float*)d_in[3];
  const float* h0    = (const float*)d_in[4];
  const float* W     = (const float*)d_in[5];
  const float* lamda = (const float*)d_in[6];
  const float* alpha = (const float*)d_in[7];
  const int*   lp    = (const int*)d_in[8];

  const int E = in_sizes[1];
  const int N = in_sizes[0] / F;
  const int NF = N * F;

  // ---- workspace layout (256B aligned regions) ----
  size_t off = 0;
  auto take = [&](size_t bytes) { size_t o = off; off += (bytes + 255) & ~(size_t)255; return o; };
  char* ws = (char*)d_ws;
  unsigned short* Wt  = (unsigned short*)(ws + take((size_t)F * F * 2));
  int* counts    = (int*)(ws + take((size_t)N * 4));
  int* row_start = (int*)(ws + take((size_t)(N + 1) * 4));
  int* fill_ptr  = (int*)(ws + take((size_t)N * 4));
  int* blk       = (int*)(ws + take(4096));
  i32x2* edges   = (i32x2*)(ws + take((size_t)E * 8));
  size_t need_base = off;
  unsigned short* xb = (unsigned short*)(ws + take((size_t)NF * 2));
  const int use_bf16 = (off <= ws_size) && ((need_base) <= ws_size);

  float* out = (float*)d_out;

  hipMemsetAsync(counts, 0, (size_t)N * sizeof(int), stream);

  int nxb = use_bf16 ? (NF + 2047) / 2048 : 0;
  prep<<<256 + nxb, 256, 0, stream>>>(W, Wt, x, xb, NF, use_bf16);

  int eb = (E + 255) / 256;
  int nb = (N + 255) / 256;  // must be <= 512 for scan2 (N=100000 -> 391)

  hist_rows<<<eb, 256, 0, stream>>>(rows, counts, E);
  scan1<<<nb, 256, 0, stream>>>(counts, row_start, blk, N);
  scan2<<<1, 512, 0, stream>>>(blk, nb);
  scan3<<<nb, 256, 0, stream>>>(counts, row_start, blk, fill_ptr, N);
  fill_csr<<<eb, 256, 0, stream>>>(rows, cols, vals, fill_ptr, (int2*)edges, E);

  int gather_blocks = (N * 64 + 255) / 256;
  if (use_bf16) {
    gather_rows_bf16<<<gather_blocks, 256, 0, stream>>>(xb, h0, row_start, edges,
                                                        out, alpha, N);
  } else {
    gather_rows_f32<<<gather_blocks, 256, 0, stream>>>(x, h0, row_start, edges,
                                                       out, alpha, N);
  }

  gemm_epilogue<<<(N + 63) / 64, 256, 0, stream>>>(out, Wt, out, lamda, lp, N);
}